// Round 4
// baseline (182.399 us; speedup 1.0000x reference)
//
#include <hip/hip_runtime.h>
#include <math.h>

#define NTOK 2048
#define HDIM 768
#define NHEAD 12

typedef __attribute__((ext_vector_type(8))) short short8v;   // 8 bf16 (4 VGPR)
typedef __attribute__((ext_vector_type(4))) float float4v;   // MFMA acc

static __device__ __forceinline__ unsigned short f2bf(float x) {
    unsigned u = __float_as_uint(x);
    return (unsigned short)((u + 0x7fffu + ((u >> 16) & 1u)) >> 16);  // RNE
}

static __device__ __forceinline__ void gload_lds16(const void* g, void* lds_uniform) {
    // LDS dest = wave-uniform base + lane*16 (hardware); global src is per-lane.
    __builtin_amdgcn_global_load_lds(
        (const __attribute__((address_space(1))) void*)g,
        (__attribute__((address_space(3))) void*)lds_uniform, 16, 0, 0);
}

// ---------------------------------------------------------------------------
// One-shot f32 -> bf16 cast of hs, Wq, Wv.  688128 float4 quads total.
// ---------------------------------------------------------------------------
__global__ __launch_bounds__(256) void cast_kernel(
    const float* __restrict__ hs, const float* __restrict__ Wq,
    const float* __restrict__ Wv, unsigned short* __restrict__ hsb,
    unsigned short* __restrict__ wqb, unsigned short* __restrict__ wvb)
{
    int gid = blockIdx.x * 256 + threadIdx.x;
    const float* src; unsigned short* dst; int off;
    if (gid < 393216)      { src = hs; dst = hsb; off = gid; }            // 2048*768/4
    else if (gid < 540672) { src = Wq; dst = wqb; off = gid - 393216; }   // +768*768/4
    else                   { src = Wv; dst = wvb; off = gid - 540672; }
    float4 v = ((const float4*)src)[off];
    union { unsigned short u[4]; unsigned long long q; } pk;
    pk.u[0] = f2bf(v.x); pk.u[1] = f2bf(v.y);
    pk.u[2] = f2bf(v.z); pk.u[3] = f2bf(v.w);
    *(unsigned long long*)(dst + (size_t)off * 4) = pk.q;
}

// ---------------------------------------------------------------------------
// Projection GEMM + fused L2-norm.  C = hs @ W^T + b.
// Tile BM=128 tokens x BN=64 features, BK=64.  grid (24,16), 256 thr (4 waves,
// each wave 32 tokens x 64 features).  x<12 -> Wq (writes normalized qbf),
// else Wv (writes vT bf16 [feature][token]).
// Staging: global_load_lds w/ T2 pre-swizzled source (byte ^= (row&7)<<4),
// double-buffered, one barrier per K-step.  Norm groups = the wave's 64-col
// (head-aligned) slice, sum-of-squares in f32 from the MFMA accumulator.
// ---------------------------------------------------------------------------
__global__ __launch_bounds__(256) void projnorm_kernel(
    const unsigned short* __restrict__ hsb, const unsigned short* __restrict__ wqb,
    const unsigned short* __restrict__ wvb, const float* __restrict__ bq,
    const float* __restrict__ bv, unsigned short* __restrict__ qbf,
    unsigned short* __restrict__ vT)
{
    __shared__ unsigned short Asb[2][128 * 64];
    __shared__ unsigned short Bsb[2][64 * 64];

    const int tid = threadIdx.x, lane = tid & 63, w = tid >> 6;
    const int m0 = blockIdx.y * 128;
    const bool isq = (blockIdx.x < 12);
    const int n0 = (blockIdx.x % 12) * 64;
    const unsigned short* Wb = (isq ? wqb : wvb) + (size_t)n0 * HDIM;
    const float* bias = isq ? bq : bv;

#define STAGEP(buf, k0)                                                        \
    {                                                                          \
        _Pragma("unroll")                                                      \
        for (int i = 0; i < 4; ++i) {          /* A: 1024 16B chunks */        \
            int ci = ((w * 4 + i) << 6) + lane;                                \
            int r = ci >> 3, c8 = (ci & 7) ^ (r & 7);                          \
            gload_lds16(hsb + (size_t)(m0 + r) * HDIM + (k0) + (c8 << 3),      \
                        (char*)&Asb[buf][0] + ((w * 4 + i) << 10));            \
        }                                                                      \
        _Pragma("unroll")                                                      \
        for (int i = 0; i < 2; ++i) {          /* B: 512 16B chunks */         \
            int ci = ((w * 2 + i) << 6) + lane;                                \
            int r = ci >> 3, c8 = (ci & 7) ^ (r & 7);                          \
            gload_lds16(Wb + (size_t)r * HDIM + (k0) + (c8 << 3),              \
                        (char*)&Bsb[buf][0] + ((w * 2 + i) << 10));            \
        }                                                                      \
    }

    float4v acc[2][4];
    #pragma unroll
    for (int fr = 0; fr < 2; ++fr)
        #pragma unroll
        for (int fc = 0; fc < 4; ++fc) acc[fr][fc] = (float4v){0.f, 0.f, 0.f, 0.f};

    STAGEP(0, 0);
    __syncthreads();

    for (int ks = 0; ks < 12; ++ks) {
        const int b = ks & 1;
        if (ks < 11) STAGEP(b ^ 1, (ks + 1) * 64);
        #pragma unroll
        for (int kk = 0; kk < 2; ++kk) {
            short8v af[2], bf[4];
            #pragma unroll
            for (int fr = 0; fr < 2; ++fr) {
                int row = w * 32 + fr * 16 + (lane & 15);
                int byt = ((row << 7) + (kk << 6) + ((lane >> 4) << 4)) ^ ((row & 7) << 4);
                af[fr] = *(const short8v*)((const char*)&Asb[b][0] + byt);
            }
            #pragma unroll
            for (int fc = 0; fc < 4; ++fc) {
                int row = fc * 16 + (lane & 15);
                int byt = ((row << 7) + (kk << 6) + ((lane >> 4) << 4)) ^ ((row & 7) << 4);
                bf[fc] = *(const short8v*)((const char*)&Bsb[b][0] + byt);
            }
            #pragma unroll
            for (int fr = 0; fr < 2; ++fr)
                #pragma unroll
                for (int fc = 0; fc < 4; ++fc)
                    acc[fr][fc] = __builtin_amdgcn_mfma_f32_16x16x32_bf16(
                        af[fr], bf[fc], acc[fr][fc], 0, 0, 0);
        }
        __syncthreads();
    }
#undef STAGEP

    float bcol[4];
    #pragma unroll
    for (int fc = 0; fc < 4; ++fc) bcol[fc] = bias[n0 + fc * 16 + (lane & 15)];

    if (isq) {
        #pragma unroll
        for (int fr = 0; fr < 2; ++fr)
            #pragma unroll
            for (int r = 0; r < 4; ++r) {
                float v[4];
                float ss = 0.f;
                #pragma unroll
                for (int fc = 0; fc < 4; ++fc) {
                    v[fc] = acc[fr][fc][r] + bcol[fc];
                    ss = fmaf(v[fc], v[fc], ss);
                }
                ss += __shfl_xor(ss, 1);
                ss += __shfl_xor(ss, 2);
                ss += __shfl_xor(ss, 4);
                ss += __shfl_xor(ss, 8);
                float inv = 1.0f / fmaxf(sqrtf(ss), 1e-12f);
                int m = m0 + w * 32 + fr * 16 + ((lane >> 4) << 2) + r;
                #pragma unroll
                for (int fc = 0; fc < 4; ++fc)
                    qbf[(size_t)m * HDIM + n0 + fc * 16 + (lane & 15)] = f2bf(v[fc] * inv);
            }
    } else {
        #pragma unroll
        for (int fr = 0; fr < 2; ++fr)
            #pragma unroll
            for (int fc = 0; fc < 4; ++fc) {
                int f = n0 + fc * 16 + (lane & 15);
                int mtk = m0 + w * 32 + fr * 16 + ((lane >> 4) << 2);
                union { unsigned short u[4]; unsigned long long q; } pk;
                #pragma unroll
                for (int r = 0; r < 4; ++r) pk.u[r] = f2bf(acc[fr][fc][r] + bcol[fc]);
                *(unsigned long long*)(vT + (size_t)f * NTOK + mtk) = pk.q;
            }
    }
}

// ---------------------------------------------------------------------------
// MFMA flash attention v2: NO K/V LDS, NO barriers.  K/V frags read directly
// from L2 (16B loads); swapped QK^T (mfma(K,Q)) so each lane owns one query's
// P-row; P redistributed via 2.3KB wave-private LDS (pitch 72 -> <=2-way).
// score softmax == exp(q.k/4) normalized (AA==BB==1 after L2-norm).
// grid 768 (=64 qtiles x 12 heads, XCD-swizzled), block 128 = 2 indep waves,
// 16 q-rows per wave, 32 key-tiles of 64.
// ---------------------------------------------------------------------------
__global__ __launch_bounds__(128) void attn_kernel(
    const unsigned short* __restrict__ qbf,   // [24576][64] bf16 normalized
    const unsigned short* __restrict__ vT,    // [768][2048] bf16
    float* __restrict__ out)                  // [24576][64] f32
{
    __shared__ unsigned short Pl[2][16 * 72];   // per-wave P: [16 q][64 k], pitch 72

    const int bid = blockIdx.x;
    const int swz = (bid & 7) * 96 + (bid >> 3);   // bijective: 768 % 8 == 0
    const int h = swz >> 6, qt = swz & 63;
    const int tid = threadIdx.x, lane = tid & 63, w = tid >> 6;
    const int n0 = qt * 32 + w * 16;

    const unsigned short* kh = qbf + (size_t)h * NTOK * 64;
    const unsigned short* vh = vT + (size_t)h * 64 * NTOK;

    // persistent Q (B-operand): col=query=lane&15, k=d=32kk+8*(lane>>4)+j
    const unsigned short* qrow = kh + ((size_t)n0 + (lane & 15)) * 64;
    short8v qa[2];
    qa[0] = *(const short8v*)(qrow + ((lane >> 4) << 3));
    qa[1] = *(const short8v*)(qrow + 32 + ((lane >> 4) << 3));

    short8v kf[8], vf[8];
#define LOADK(mb)                                                              \
    _Pragma("unroll")                                                          \
    for (int t = 0; t < 4; ++t)                                                \
        _Pragma("unroll")                                                      \
        for (int kk = 0; kk < 2; ++kk)                                         \
            kf[t * 2 + kk] = *(const short8v*)(                                \
                kh + ((size_t)((mb) + t * 16 + (lane & 15))) * 64 +            \
                kk * 32 + ((lane >> 4) << 3));
#define LOADV(mb)                                                              \
    _Pragma("unroll")                                                          \
    for (int t = 0; t < 4; ++t)                                                \
        _Pragma("unroll")                                                      \
        for (int kk = 0; kk < 2; ++kk)                                         \
            vf[t * 2 + kk] = *(const short8v*)(                                \
                vh + (size_t)(t * 16 + (lane & 15)) * NTOK + (mb) +            \
                kk * 32 + ((lane >> 4) << 3));

    float4v acc[4];
    #pragma unroll
    for (int t = 0; t < 4; ++t) acc[t] = (float4v){0.f, 0.f, 0.f, 0.f};
    float lsum = 0.f;

    LOADK(0);
    LOADV(0);

    for (int mt = 0; mt < 32; ++mt) {
        // ---- S^T = K.Q^T : lane = query lane&15, keys t*16+(lane>>4)*4+r
        float4v St[4];
        __builtin_amdgcn_s_setprio(1);
        #pragma unroll
        for (int t = 0; t < 4; ++t) {
            St[t] = (float4v){0.f, 0.f, 0.f, 0.f};
            St[t] = __builtin_amdgcn_mfma_f32_16x16x32_bf16(kf[t*2+0], qa[0], St[t], 0, 0, 0);
            St[t] = __builtin_amdgcn_mfma_f32_16x16x32_bf16(kf[t*2+1], qa[1], St[t], 0, 0, 0);
        }
        __builtin_amdgcn_s_setprio(0);

        if (mt < 31) LOADK((mt + 1) * 64);   // prefetch next K (kf free now)

        // ---- softmax numerators (score bounded in [-0.5,0]: no max pass)
        float p[4][4];
        float ls = 0.f;
        #pragma unroll
        for (int t = 0; t < 4; ++t)
            #pragma unroll
            for (int r = 0; r < 4; ++r) {
                p[t][r] = __expf(St[t][r] * 0.25f);
                ls += p[t][r];
            }
        ls += __shfl_xor(ls, 16);
        ls += __shfl_xor(ls, 32);
        lsum += ls;

        // ---- pack P (bf16) -> wave-private LDS, redistribute for PV A-frags
        #pragma unroll
        for (int t = 0; t < 4; ++t) {
            unsigned w0, w1;
            asm volatile("v_cvt_pk_bf16_f32 %0, %1, %2"
                         : "=v"(w0) : "v"(p[t][0]), "v"(p[t][1]));
            asm volatile("v_cvt_pk_bf16_f32 %0, %1, %2"
                         : "=v"(w1) : "v"(p[t][2]), "v"(p[t][3]));
            unsigned long long q64 = (unsigned long long)w0 |
                                     ((unsigned long long)w1 << 32);
            *(unsigned long long*)(&Pl[w][(lane & 15) * 72 + t * 16 +
                                          ((lane >> 4) << 2)]) = q64;
        }
        asm volatile("s_waitcnt lgkmcnt(0)" ::: "memory");
        __builtin_amdgcn_sched_barrier(0);

        short8v pf[2];
        #pragma unroll
        for (int kk = 0; kk < 2; ++kk)
            pf[kk] = *(const short8v*)(&Pl[w][(lane & 15) * 72 + kk * 32 +
                                              ((lane >> 4) << 3)]);

        // ---- acc += P @ V
        __builtin_amdgcn_s_setprio(1);
        #pragma unroll
        for (int t = 0; t < 4; ++t) {
            acc[t] = __builtin_amdgcn_mfma_f32_16x16x32_bf16(pf[0], vf[t*2+0], acc[t], 0, 0, 0);
            acc[t] = __builtin_amdgcn_mfma_f32_16x16x32_bf16(pf[1], vf[t*2+1], acc[t], 0, 0, 0);
        }
        __builtin_amdgcn_s_setprio(0);

        if (mt < 31) LOADV((mt + 1) * 64);   // prefetch next V (vf free now)
    }
#undef LOADK
#undef LOADV

    // ---- finalize: lane needs lsum of query (lane>>4)*4+r (held by lane q)
    #pragma unroll
    for (int r = 0; r < 4; ++r) {
        float lv = __shfl(lsum, ((lane >> 4) << 2) + r);
        float inv = 1.0f / lv;
        int n = n0 + ((lane >> 4) << 2) + r;
        #pragma unroll
        for (int t = 0; t < 4; ++t)
            out[((size_t)h * NTOK + n) * 64 + t * 16 + (lane & 15)] = acc[t][r] * inv;
    }
}

// ---------------------------------------------------------------------------
extern "C" void kernel_launch(void* const* d_in, const int* in_sizes, int n_in,
                              void* d_out, int out_size, void* d_ws, size_t ws_size,
                              hipStream_t stream)
{
    const float* hs = (const float*)d_in[0];
    // d_in[1] = g, d_in[2] = attention_mask: feed only dead code -> unused.
    const float* Wq = (const float*)d_in[3];
    const float* bq = (const float*)d_in[4];
    const float* Wv = (const float*)d_in[5];
    const float* bv = (const float*)d_in[6];
    float* out = (float*)d_out;

    unsigned short* hsb = (unsigned short*)d_ws;            // 2048*768
    unsigned short* wqb = hsb + (size_t)NTOK * HDIM;        // 768*768
    unsigned short* wvb = wqb + (size_t)HDIM * HDIM;        // 768*768
    unsigned short* qbf = wvb + (size_t)HDIM * HDIM;        // 2048*768 (normalized q)
    unsigned short* vT  = qbf + (size_t)NTOK * HDIM;        // 768*2048 (v transposed)

    cast_kernel<<<dim3(2688), 256, 0, stream>>>(hs, Wq, Wv, hsb, wqb, wvb);
    projnorm_kernel<<<dim3(24, 16), 256, 0, stream>>>(hsb, wqb, wvb, bq, bv, qbf, vT);
    attn_kernel<<<dim3(768), 128, 0, stream>>>(qbf, vT, out);
}

// Round 6
// 154.473 us; speedup vs baseline: 1.1808x; 1.1808x over previous
//
#include <hip/hip_runtime.h>
#include <math.h>

#define NTOK 2048
#define HDIM 768
#define NHEAD 12
#define NQ (NTOK * NHEAD)   // 24576 total query-vectors

typedef __attribute__((ext_vector_type(8))) short short8v;   // 8 bf16 (4 VGPR)
typedef __attribute__((ext_vector_type(4))) float float4v;   // MFMA acc

static __device__ __forceinline__ unsigned short f2bf(float x) {
    unsigned u = __float_as_uint(x);
    return (unsigned short)((u + 0x7fffu + ((u >> 16) & 1u)) >> 16);  // RNE
}
static __device__ __forceinline__ unsigned pk2(float a, float b) {   // [lo=a, hi=b]
    unsigned r;
    asm("v_cvt_pk_bf16_f32 %0, %1, %2" : "=v"(r) : "v"(a), "v"(b));
    return r;
}
static __device__ __forceinline__ void gload_lds16(const void* g, void* lds_uniform) {
    __builtin_amdgcn_global_load_lds(
        (const __attribute__((address_space(1))) void*)g,
        (__attribute__((address_space(3))) void*)lds_uniform, 16, 0, 0);
}

// ---------------------------------------------------------------------------
// Projection GEMM + fused cast + fused L2-norm.  C = hs @ W^T + b.
// grid (12,16,2): x = 64-feature tile (head-aligned), y = 128-token tile,
// z selects {Wq->qbf normalized, Wv->vT}.  block 256 = 4 waves, wave = 32
// tokens.  BK=32.  Staging: f32 global -> regs -> cvt_pk -> LDS bf16
// (pitch 40 ushort = 80B rows: 16B-aligned, 2-way banked frag reads = free).
// Double-buffered LDS, one barrier per K-step.
// ---------------------------------------------------------------------------
__global__ __launch_bounds__(256) void projnorm_kernel(
    const float* __restrict__ hs, const float* __restrict__ Wq,
    const float* __restrict__ bq, const float* __restrict__ Wv,
    const float* __restrict__ bv, unsigned short* __restrict__ qbf,
    unsigned short* __restrict__ vT)
{
    constexpr int PITCH = 40;
    __shared__ unsigned short As[2][128 * PITCH];
    __shared__ unsigned short Bs[2][64 * PITCH];

    const bool isq = (blockIdx.z == 0);
    const float* W    = isq ? Wq : Wv;
    const float* bias = isq ? bq : bv;
    const int n0 = blockIdx.x * 64, m0 = blockIdx.y * 128;
    const int tid = threadIdx.x, lane = tid & 63, w = tid >> 6;

    const int arow = tid >> 1, acol = (tid & 1) * 16;   // A: 128 rows x 32 cols
    const int brow = tid >> 2, bcol = (tid & 3) * 8;    // B: 64 rows x 32 cols
    const float* ag = hs + (size_t)(m0 + arow) * HDIM + acol;
    const float* bg = W + (size_t)(n0 + brow) * HDIM + bcol;

    float4 ga[4], gb[2];
#define PLOAD(k0)                                                              \
    {                                                                          \
        _Pragma("unroll") for (int i = 0; i < 4; ++i)                          \
            ga[i] = *(const float4*)(ag + (k0) + i * 4);                       \
        _Pragma("unroll") for (int i = 0; i < 2; ++i)                          \
            gb[i] = *(const float4*)(bg + (k0) + i * 4);                       \
    }
#define PCVTW(b)                                                               \
    {                                                                          \
        uint4 u0 = {pk2(ga[0].x, ga[0].y), pk2(ga[0].z, ga[0].w),              \
                    pk2(ga[1].x, ga[1].y), pk2(ga[1].z, ga[1].w)};             \
        uint4 u1 = {pk2(ga[2].x, ga[2].y), pk2(ga[2].z, ga[2].w),              \
                    pk2(ga[3].x, ga[3].y), pk2(ga[3].z, ga[3].w)};             \
        *(uint4*)&As[b][arow * PITCH + acol]     = u0;                         \
        *(uint4*)&As[b][arow * PITCH + acol + 8] = u1;                         \
        uint4 u2 = {pk2(gb[0].x, gb[0].y), pk2(gb[0].z, gb[0].w),              \
                    pk2(gb[1].x, gb[1].y), pk2(gb[1].z, gb[1].w)};             \
        *(uint4*)&Bs[b][brow * PITCH + bcol] = u2;                             \
    }

    float4v acc[2][4];
    #pragma unroll
    for (int fr = 0; fr < 2; ++fr)
        #pragma unroll
        for (int fc = 0; fc < 4; ++fc) acc[fr][fc] = (float4v){0.f, 0.f, 0.f, 0.f};

    PLOAD(0);
    PCVTW(0);

    for (int ks = 0; ks < 24; ++ks) {
        const int b = ks & 1;
        if (ks < 23) PLOAD((ks + 1) * 32);
        __syncthreads();                       // LDS[b] visible to all waves
        short8v af[2], bf[4];
        #pragma unroll
        for (int fr = 0; fr < 2; ++fr)
            af[fr] = *(const short8v*)
                &As[b][(w * 32 + fr * 16 + (lane & 15)) * PITCH + ((lane >> 4) << 3)];
        #pragma unroll
        for (int fc = 0; fc < 4; ++fc)
            bf[fc] = *(const short8v*)
                &Bs[b][(fc * 16 + (lane & 15)) * PITCH + ((lane >> 4) << 3)];
        #pragma unroll
        for (int fr = 0; fr < 2; ++fr)
            #pragma unroll
            for (int fc = 0; fc < 4; ++fc)
                acc[fr][fc] = __builtin_amdgcn_mfma_f32_16x16x32_bf16(
                    af[fr], bf[fc], acc[fr][fc], 0, 0, 0);
        if (ks < 23) PCVTW(b ^ 1);             // safe: b^1 last read before barrier
    }
#undef PLOAD
#undef PCVTW

    float bcol4[4];
    #pragma unroll
    for (int fc = 0; fc < 4; ++fc) bcol4[fc] = bias[n0 + fc * 16 + (lane & 15)];

    if (isq) {
        #pragma unroll
        for (int fr = 0; fr < 2; ++fr)
            #pragma unroll
            for (int r = 0; r < 4; ++r) {
                float v[4];
                float ss = 0.f;
                #pragma unroll
                for (int fc = 0; fc < 4; ++fc) {
                    v[fc] = acc[fr][fc][r] + bcol4[fc];
                    ss = fmaf(v[fc], v[fc], ss);
                }
                ss += __shfl_xor(ss, 1);
                ss += __shfl_xor(ss, 2);
                ss += __shfl_xor(ss, 4);
                ss += __shfl_xor(ss, 8);
                float inv = 1.0f / fmaxf(sqrtf(ss), 1e-12f);
                int m = m0 + w * 32 + fr * 16 + ((lane >> 4) << 2) + r;
                #pragma unroll
                for (int fc = 0; fc < 4; ++fc)
                    qbf[(size_t)m * HDIM + n0 + fc * 16 + (lane & 15)] = f2bf(v[fc] * inv);
            }
    } else {
        #pragma unroll
        for (int fr = 0; fr < 2; ++fr)
            #pragma unroll
            for (int fc = 0; fc < 4; ++fc) {
                int f = n0 + fc * 16 + (lane & 15);
                int mtk = m0 + w * 32 + fr * 16 + ((lane >> 4) << 2);
                union { unsigned short u[4]; unsigned long long q; } pk;
                #pragma unroll
                for (int r = 0; r < 4; ++r) pk.u[r] = f2bf(acc[fr][fc][r] + bcol4[fc]);
                *(unsigned long long*)(vT + (size_t)f * NTOK + mtk) = pk.q;
            }
    }
}

// ---------------------------------------------------------------------------
// MFMA flash attention v3, K-split x2.  softmax == exp(q.k/4) normalized.
// grid 1536 = 12 h x 64 qtiles(32q) x 2 k-halves (XCD-swizzled); block 128
// = 2 waves, wave = 16 queries x 1024 keys (16 tiles of 64).
// K tile: LDS via global_load_lds (swizzled source), double-buffered, counted
// vmcnt(8) + raw s_barrier per tile (V reg-loads stay in flight across it).
// V tile: direct L2 -> regs (vf[8]), prefetched right after PV consumes it.
// P: cvt_pk -> wave-private LDS slab (pitch 72).  Partials: numerator to
// out/part1 (no division), lsum to lbuf; combine kernel finishes.
// LDS 20.5 KB -> 7 blocks/CU cap; 6 resident (grid/256).  launch_bounds(128,3).
// ---------------------------------------------------------------------------
__global__ __launch_bounds__(128, 3) void attn_kernel(
    const unsigned short* __restrict__ qbf,   // [24576][64] bf16 normalized
    const unsigned short* __restrict__ vT,    // [768][2048] bf16
    float* __restrict__ num0,                 // = d_out, ksp 0 numerator
    float* __restrict__ part1,                // ksp 1 numerator
    float* __restrict__ lbuf)                 // [2][24576] denominators
{
    __shared__ unsigned short Ksb[2][64 * 64];
    __shared__ unsigned short Pl[2][16 * 72];

    const int bid = blockIdx.x;
    const int swz = (bid & 7) * 192 + (bid >> 3);   // bijective: 1536 % 8 == 0
    const int h = swz >> 7, rem = swz & 127;
    const int qt = rem >> 1, ksp = rem & 1;
    const int tid = threadIdx.x, lane = tid & 63, w = tid >> 6;
    const int n0 = qt * 32;
    const int kbase0 = ksp * 1024;

    const unsigned short* kh = qbf + (size_t)h * NTOK * 64;
    const unsigned short* vh = vT + (size_t)h * 64 * NTOK;

    const unsigned short* qrow = kh + ((size_t)n0 + w * 16 + (lane & 15)) * 64;
    short8v qa[2];
    qa[0] = *(const short8v*)(qrow + ((lane >> 4) << 3));
    qa[1] = *(const short8v*)(qrow + 32 + ((lane >> 4) << 3));

#define STAGE_K(buf, m0v)                                                      \
    {                                                                          \
        _Pragma("unroll")                                                      \
        for (int i = 0; i < 4; ++i) {        /* 512 x 16B chunks, 128 thr */   \
            int ci = ((w * 4 + i) << 6) + lane;                                \
            int r = ci >> 3, c8 = (ci & 7) ^ (r & 7);                          \
            gload_lds16(kh + ((size_t)(m0v) + r) * 64 + (c8 << 3),             \
                        (char*)&Ksb[buf][0] + ((w * 4 + i) << 10));            \
        }                                                                      \
    }
    short8v vf[8];
#define LOADV(mb)                                                              \
    _Pragma("unroll")                                                          \
    for (int t = 0; t < 4; ++t)                                                \
        _Pragma("unroll")                                                      \
        for (int kk = 0; kk < 2; ++kk)                                         \
            vf[t * 2 + kk] = *(const short8v*)(                                \
                vh + (size_t)(t * 16 + (lane & 15)) * NTOK + (mb) +            \
                kk * 32 + ((lane >> 4) << 3));

    float4v acc[4];
    #pragma unroll
    for (int t = 0; t < 4; ++t) acc[t] = (float4v){0.f, 0.f, 0.f, 0.f};
    float lsum = 0.f;

    STAGE_K(0, kbase0);
    LOADV(kbase0);
    __syncthreads();                        // prologue: full drain, all ready

    for (int mt = 0; mt < 16; ++mt) {
        const int cur = mt & 1;
        if (mt < 15) STAGE_K(cur ^ 1, kbase0 + (mt + 1) * 64);   // 4 DMA in flight

        // ---- S^T = K.Q^T  (keys t*16+(lane>>4)*4+r, query lane&15)
        float4v St[4];
        __builtin_amdgcn_s_setprio(1);
        #pragma unroll
        for (int t = 0; t < 4; ++t) {
            St[t] = (float4v){0.f, 0.f, 0.f, 0.f};
            #pragma unroll
            for (int kk = 0; kk < 2; ++kk) {
                int row = (lane & 15) + (t << 4);
                int off = ((row << 7) + (kk << 6) + ((lane >> 4) << 4)) ^ ((row & 7) << 4);
                short8v kf = *(const short8v*)((const char*)&Ksb[cur][0] + off);
                St[t] = __builtin_amdgcn_mfma_f32_16x16x32_bf16(kf, qa[kk], St[t], 0, 0, 0);
            }
        }
        __builtin_amdgcn_s_setprio(0);

        // ---- softmax numerators (scores in [-0.5,0]: no max pass needed)
        float p[4][4];
        float ls = 0.f;
        #pragma unroll
        for (int t = 0; t < 4; ++t)
            #pragma unroll
            for (int r = 0; r < 4; ++r) {
                p[t][r] = __expf(St[t][r] * 0.25f);
                ls += p[t][r];
            }
        ls += __shfl_xor(ls, 16);
        ls += __shfl_xor(ls, 32);
        lsum += ls;

        // ---- pack P -> wave-private LDS, reload as PV A-frags
        #pragma unroll
        for (int t = 0; t < 4; ++t) {
            unsigned w0 = pk2(p[t][0], p[t][1]);
            unsigned w1 = pk2(p[t][2], p[t][3]);
            unsigned long long q64 =
                (unsigned long long)w0 | ((unsigned long long)w1 << 32);
            *(unsigned long long*)(&Pl[w][(lane & 15) * 72 + t * 16 +
                                          ((lane >> 4) << 2)]) = q64;
        }
        asm volatile("s_waitcnt lgkmcnt(0)" ::: "memory");
        __builtin_amdgcn_sched_barrier(0);
        short8v pf[2];
        #pragma unroll
        for (int kk = 0; kk < 2; ++kk)
            pf[kk] = *(const short8v*)(&Pl[w][(lane & 15) * 72 + kk * 32 +
                                              ((lane >> 4) << 3)]);

        // ---- acc += P @ V   (compiler emits vmcnt waits for vf: DMA stays live)
        __builtin_amdgcn_s_setprio(1);
        #pragma unroll
        for (int t = 0; t < 4; ++t) {
            acc[t] = __builtin_amdgcn_mfma_f32_16x16x32_bf16(pf[0], vf[t*2+0], acc[t], 0, 0, 0);
            acc[t] = __builtin_amdgcn_mfma_f32_16x16x32_bf16(pf[1], vf[t*2+1], acc[t], 0, 0, 0);
        }
        __builtin_amdgcn_s_setprio(0);

        if (mt < 15) {
            LOADV(kbase0 + (mt + 1) * 64);   // 8 V loads: outstanding = 4 DMA + 8 V
            asm volatile("s_waitcnt vmcnt(8)" ::: "memory");  // retire K-DMA only
            __builtin_amdgcn_s_barrier();                      // raw: V stays in flight
            __builtin_amdgcn_sched_barrier(0);
        }
    }
#undef STAGE_K
#undef LOADV

    // ---- partial stores (numerator un-normalized, denominator separate)
    float* nout = ksp ? part1 : num0;
    #pragma unroll
    for (int r = 0; r < 4; ++r) {
        int n = n0 + w * 16 + ((lane >> 4) << 2) + r;
        #pragma unroll
        for (int t = 0; t < 4; ++t)
            nout[((size_t)h * NTOK + n) * 64 + t * 16 + (lane & 15)] = acc[t][r];
    }
    if (lane < 16)
        lbuf[ksp * NQ + h * NTOK + n0 + w * 16 + lane] = lsum;
}

// ---------------------------------------------------------------------------
// out = (num0 + part1) / (l0 + l1), float4-vectorized.  393216 float4s.
// ---------------------------------------------------------------------------
__global__ __launch_bounds__(256) void combine_kernel(
    float* __restrict__ out, const float* __restrict__ part1,
    const float* __restrict__ lbuf)
{
    int gid = blockIdx.x * 256 + threadIdx.x;
    float4 a = ((const float4*)out)[gid];
    float4 b = ((const float4*)part1)[gid];
    int row = gid >> 4;
    float inv = 1.0f / (lbuf[row] + lbuf[NQ + row]);
    float4 o;
    o.x = (a.x + b.x) * inv; o.y = (a.y + b.y) * inv;
    o.z = (a.z + b.z) * inv; o.w = (a.w + b.w) * inv;
    ((float4*)out)[gid] = o;
}

// ---------------------------------------------------------------------------
extern "C" void kernel_launch(void* const* d_in, const int* in_sizes, int n_in,
                              void* d_out, int out_size, void* d_ws, size_t ws_size,
                              hipStream_t stream)
{
    const float* hs = (const float*)d_in[0];
    // d_in[1] = g, d_in[2] = attention_mask: feed only dead code -> unused.
    const float* Wq = (const float*)d_in[3];
    const float* bq = (const float*)d_in[4];
    const float* Wv = (const float*)d_in[5];
    const float* bv = (const float*)d_in[6];
    float* out = (float*)d_out;

    unsigned short* qbf   = (unsigned short*)d_ws;            // [2048*768] bf16
    unsigned short* vT    = qbf + (size_t)NTOK * HDIM;        // [768*2048] bf16
    float*          part1 = (float*)(vT + (size_t)HDIM * NTOK);   // [24576*64] f32
    float*          lbuf  = part1 + (size_t)NQ * 64;          // [2*24576] f32

    projnorm_kernel<<<dim3(12, 16, 2), 256, 0, stream>>>(
        hs, Wq, bq, Wv, bv, qbf, vT);
    attn_kernel<<<dim3(1536), 128, 0, stream>>>(qbf, vT, out, part1, lbuf);
    combine_kernel<<<dim3(1536), 256, 0, stream>>>(out, part1, lbuf);
}

// Round 8
// 153.944 us; speedup vs baseline: 1.1848x; 1.0034x over previous
//
#include <hip/hip_runtime.h>
#include <math.h>

#define NTOK 2048
#define HDIM 768
#define NHEAD 12
#define NQ (NTOK * NHEAD)   // 24576 total query-vectors

typedef __attribute__((ext_vector_type(8))) short short8v;   // 8 bf16 (4 VGPR)
typedef __attribute__((ext_vector_type(4))) float float4v;   // MFMA acc

static __device__ __forceinline__ unsigned short f2bf(float x) {
    unsigned u = __float_as_uint(x);
    return (unsigned short)((u + 0x7fffu + ((u >> 16) & 1u)) >> 16);  // RNE
}
static __device__ __forceinline__ unsigned pk2(float a, float b) {   // [lo=a, hi=b]
    unsigned r;
    asm("v_cvt_pk_bf16_f32 %0, %1, %2" : "=v"(r) : "v"(a), "v"(b));
    return r;
}
static __device__ __forceinline__ void gload_lds16(const void* g, void* lds_uniform) {
    __builtin_amdgcn_global_load_lds(
        (const __attribute__((address_space(1))) void*)g,
        (__attribute__((address_space(3))) void*)lds_uniform, 16, 0, 0);
}

// ---------------------------------------------------------------------------
// Projection GEMM + fused cast + fused L2-norm.  (unchanged from round 6,
// passed at absmax 2.4e-4, ~15us)
// ---------------------------------------------------------------------------
__global__ __launch_bounds__(256) void projnorm_kernel(
    const float* __restrict__ hs, const float* __restrict__ Wq,
    const float* __restrict__ bq, const float* __restrict__ Wv,
    const float* __restrict__ bv, unsigned short* __restrict__ qbf,
    unsigned short* __restrict__ vT)
{
    constexpr int PITCH = 40;
    __shared__ unsigned short As[2][128 * PITCH];
    __shared__ unsigned short Bs[2][64 * PITCH];

    const bool isq = (blockIdx.z == 0);
    const float* W    = isq ? Wq : Wv;
    const float* bias = isq ? bq : bv;
    const int n0 = blockIdx.x * 64, m0 = blockIdx.y * 128;
    const int tid = threadIdx.x, lane = tid & 63, w = tid >> 6;

    const int arow = tid >> 1, acol = (tid & 1) * 16;   // A: 128 rows x 32 cols
    const int brow = tid >> 2, bcol = (tid & 3) * 8;    // B: 64 rows x 32 cols
    const float* ag = hs + (size_t)(m0 + arow) * HDIM + acol;
    const float* bg = W + (size_t)(n0 + brow) * HDIM + bcol;

    float4 ga[4], gb[2];
#define PLOAD(k0)                                                              \
    {                                                                          \
        _Pragma("unroll") for (int i = 0; i < 4; ++i)                          \
            ga[i] = *(const float4*)(ag + (k0) + i * 4);                       \
        _Pragma("unroll") for (int i = 0; i < 2; ++i)                          \
            gb[i] = *(const float4*)(bg + (k0) + i * 4);                       \
    }
#define PCVTW(b)                                                               \
    {                                                                          \
        uint4 u0 = {pk2(ga[0].x, ga[0].y), pk2(ga[0].z, ga[0].w),              \
                    pk2(ga[1].x, ga[1].y), pk2(ga[1].z, ga[1].w)};             \
        uint4 u1 = {pk2(ga[2].x, ga[2].y), pk2(ga[2].z, ga[2].w),              \
                    pk2(ga[3].x, ga[3].y), pk2(ga[3].z, ga[3].w)};             \
        *(uint4*)&As[b][arow * PITCH + acol]     = u0;                         \
        *(uint4*)&As[b][arow * PITCH + acol + 8] = u1;                         \
        uint4 u2 = {pk2(gb[0].x, gb[0].y), pk2(gb[0].z, gb[0].w),              \
                    pk2(gb[1].x, gb[1].y), pk2(gb[1].z, gb[1].w)};             \
        *(uint4*)&Bs[b][brow * PITCH + bcol] = u2;                             \
    }

    float4v acc[2][4];
    #pragma unroll
    for (int fr = 0; fr < 2; ++fr)
        #pragma unroll
        for (int fc = 0; fc < 4; ++fc) acc[fr][fc] = (float4v){0.f, 0.f, 0.f, 0.f};

    PLOAD(0);
    PCVTW(0);

    for (int ks = 0; ks < 24; ++ks) {
        const int b = ks & 1;
        if (ks < 23) PLOAD((ks + 1) * 32);
        __syncthreads();                       // LDS[b] visible to all waves
        short8v af[2], bf[4];
        #pragma unroll
        for (int fr = 0; fr < 2; ++fr)
            af[fr] = *(const short8v*)
                &As[b][(w * 32 + fr * 16 + (lane & 15)) * PITCH + ((lane >> 4) << 3)];
        #pragma unroll
        for (int fc = 0; fc < 4; ++fc)
            bf[fc] = *(const short8v*)
                &Bs[b][(fc * 16 + (lane & 15)) * PITCH + ((lane >> 4) << 3)];
        #pragma unroll
        for (int fr = 0; fr < 2; ++fr)
            #pragma unroll
            for (int fc = 0; fc < 4; ++fc)
                acc[fr][fc] = __builtin_amdgcn_mfma_f32_16x16x32_bf16(
                    af[fr], bf[fc], acc[fr][fc], 0, 0, 0);
        if (ks < 23) PCVTW(b ^ 1);             // safe: b^1 last read before barrier
    }
#undef PLOAD
#undef PCVTW

    float bcol4[4];
    #pragma unroll
    for (int fc = 0; fc < 4; ++fc) bcol4[fc] = bias[n0 + fc * 16 + (lane & 15)];

    if (isq) {
        #pragma unroll
        for (int fr = 0; fr < 2; ++fr)
            #pragma unroll
            for (int r = 0; r < 4; ++r) {
                float v[4];
                float ss = 0.f;
                #pragma unroll
                for (int fc = 0; fc < 4; ++fc) {
                    v[fc] = acc[fr][fc][r] + bcol4[fc];
                    ss = fmaf(v[fc], v[fc], ss);
                }
                ss += __shfl_xor(ss, 1);
                ss += __shfl_xor(ss, 2);
                ss += __shfl_xor(ss, 4);
                ss += __shfl_xor(ss, 8);
                float inv = 1.0f / fmaxf(sqrtf(ss), 1e-12f);
                int m = m0 + w * 32 + fr * 16 + ((lane >> 4) << 2) + r;
                #pragma unroll
                for (int fc = 0; fc < 4; ++fc)
                    qbf[(size_t)m * HDIM + n0 + fc * 16 + (lane & 15)] = f2bf(v[fc] * inv);
            }
    } else {
        #pragma unroll
        for (int fr = 0; fr < 2; ++fr)
            #pragma unroll
            for (int fc = 0; fc < 4; ++fc) {
                int f = n0 + fc * 16 + (lane & 15);
                int mtk = m0 + w * 32 + fr * 16 + ((lane >> 4) << 2);
                union { unsigned short u[4]; unsigned long long q; } pk;
                #pragma unroll
                for (int r = 0; r < 4; ++r) pk.u[r] = f2bf(acc[fr][fc][r] + bcol4[fc]);
                *(unsigned long long*)(vT + (size_t)f * NTOK + mtk) = pk.q;
            }
    }
}

// ---------------------------------------------------------------------------
// MFMA flash attention v4, K-split x2.  Same math/layout as v3 (passed), but:
// - amdgpu_waves_per_eu(3,3): scheduler targets exactly 3 waves/EU (VGPR cap
//   ~170) instead of minimizing to 56 VGPRs -> prefetch can live in registers.
// - V explicitly double-buffered (vfA/vfB, 2x-unrolled loop, all indices
//   compile-time), loads issued at TOP of each tile with the K-DMA and pinned
//   by sched_barrier(0) so they cannot be sunk to their use.
// - per tile in flight: 4 K-DMA + 8 V loads; vmcnt(8) retires K-DMA before
//   raw s_barrier; V rides across, waited by compiler (vmcnt(12)) at next PV.
// ---------------------------------------------------------------------------
__global__ __launch_bounds__(128)
__attribute__((amdgpu_waves_per_eu(3, 3)))
void attn_kernel(
    const unsigned short* __restrict__ qbf,   // [24576][64] bf16 normalized
    const unsigned short* __restrict__ vT,    // [768][2048] bf16
    float* __restrict__ num0,                 // = d_out, ksp 0 numerator
    float* __restrict__ part1,                // ksp 1 numerator
    float* __restrict__ lbuf)                 // [2][24576] denominators
{
    __shared__ unsigned short Ksb[2][64 * 64];
    __shared__ unsigned short Pl[2][16 * 72];

    const int bid = blockIdx.x;
    const int swz = (bid & 7) * 192 + (bid >> 3);   // bijective: 1536 % 8 == 0
    const int h = swz >> 7, rem = swz & 127;
    const int qt = rem >> 1, ksp = rem & 1;
    const int tid = threadIdx.x, lane = tid & 63, w = tid >> 6;
    const int n0 = qt * 32;
    const int kbase0 = ksp * 1024;

    const unsigned short* kh = qbf + (size_t)h * NTOK * 64;
    const unsigned short* vh = vT + (size_t)h * 64 * NTOK;

    const unsigned short* qrow = kh + ((size_t)n0 + w * 16 + (lane & 15)) * 64;
    short8v qa[2];
    qa[0] = *(const short8v*)(qrow + ((lane >> 4) << 3));
    qa[1] = *(const short8v*)(qrow + 32 + ((lane >> 4) << 3));

#define STAGE_K(buf, m0v)                                                      \
    {                                                                          \
        _Pragma("unroll")                                                      \
        for (int i = 0; i < 4; ++i) {        /* 512 x 16B chunks, 128 thr */   \
            int ci = ((w * 4 + i) << 6) + lane;                                \
            int r = ci >> 3, c8 = (ci & 7) ^ (r & 7);                          \
            gload_lds16(kh + ((size_t)(m0v) + r) * 64 + (c8 << 3),             \
                        (char*)&Ksb[buf][0] + ((w * 4 + i) << 10));            \
        }                                                                      \
    }
    short8v vfA[8], vfB[8];
#define LOADV(VF, mb)                                                          \
    _Pragma("unroll")                                                          \
    for (int t = 0; t < 4; ++t)                                                \
        _Pragma("unroll")                                                      \
        for (int kk = 0; kk < 2; ++kk)                                         \
            VF[t * 2 + kk] = *(const short8v*)(                                \
                vh + (size_t)(t * 16 + (lane & 15)) * NTOK + (mb) +            \
                kk * 32 + ((lane >> 4) << 3));

    float4v acc[4];
    #pragma unroll
    for (int t = 0; t < 4; ++t) acc[t] = (float4v){0.f, 0.f, 0.f, 0.f};
    float lsum = 0.f;

// One tile: MT = tile index (runtime ok), KB = K LDS buffer (compile-time),
// VFC = V regs for this tile, VFN = V regs to prefetch, LAST = no prefetch.
#define TILE_BODY(MT, KB, VFC, VFN, LAST)                                      \
    {                                                                          \
        if (!(LAST)) {                                                         \
            STAGE_K((KB) ^ 1, kbase0 + ((MT) + 1) * 64);                       \
            LOADV(VFN, kbase0 + ((MT) + 1) * 64);                              \
            __builtin_amdgcn_sched_barrier(0);   /* pin issue point */         \
        }                                                                      \
        /* S^T = K.Q^T (keys t*16+(lane>>4)*4+r, query lane&15) */             \
        float4v St[4];                                                         \
        __builtin_amdgcn_s_setprio(1);                                         \
        _Pragma("unroll")                                                      \
        for (int t = 0; t < 4; ++t) {                                          \
            St[t] = (float4v){0.f, 0.f, 0.f, 0.f};                             \
            _Pragma("unroll")                                                  \
            for (int kk = 0; kk < 2; ++kk) {                                   \
                int row = (lane & 15) + (t << 4);                              \
                int off = ((row << 7) + (kk << 6) + ((lane >> 4) << 4)) ^      \
                          ((row & 7) << 4);                                    \
                short8v kf = *(const short8v*)((const char*)&Ksb[KB][0] + off);\
                St[t] = __builtin_amdgcn_mfma_f32_16x16x32_bf16(               \
                    kf, qa[kk], St[t], 0, 0, 0);                               \
            }                                                                  \
        }                                                                      \
        __builtin_amdgcn_s_setprio(0);                                         \
        /* softmax numerators (scores in [-0.5,0]: no max pass) */             \
        float p[4][4];                                                         \
        float ls = 0.f;                                                        \
        _Pragma("unroll")                                                      \
        for (int t = 0; t < 4; ++t)                                            \
            _Pragma("unroll")                                                  \
            for (int r = 0; r < 4; ++r) {                                      \
                p[t][r] = __expf(St[t][r] * 0.25f);                            \
                ls += p[t][r];                                                 \
            }                                                                  \
        ls += __shfl_xor(ls, 16);                                              \
        ls += __shfl_xor(ls, 32);                                              \
        lsum += ls;                                                            \
        /* pack P -> wave-private LDS, reload as PV A-frags */                 \
        _Pragma("unroll")                                                      \
        for (int t = 0; t < 4; ++t) {                                          \
            unsigned w0 = pk2(p[t][0], p[t][1]);                               \
            unsigned w1 = pk2(p[t][2], p[t][3]);                               \
            unsigned long long q64 =                                           \
                (unsigned long long)w0 | ((unsigned long long)w1 << 32);       \
            *(unsigned long long*)(&Pl[w][(lane & 15) * 72 + t * 16 +          \
                                          ((lane >> 4) << 2)]) = q64;          \
        }                                                                      \
        asm volatile("s_waitcnt lgkmcnt(0)" ::: "memory");                     \
        __builtin_amdgcn_sched_barrier(0);                                     \
        short8v pf[2];                                                         \
        _Pragma("unroll")                                                      \
        for (int kk = 0; kk < 2; ++kk)                                         \
            pf[kk] = *(const short8v*)(&Pl[w][(lane & 15) * 72 + kk * 32 +     \
                                              ((lane >> 4) << 3)]);            \
        /* acc += P @ V (VFC loaded one tile ago; compiler waits vmcnt(12)) */ \
        __builtin_amdgcn_s_setprio(1);                                         \
        _Pragma("unroll")                                                      \
        for (int t = 0; t < 4; ++t) {                                          \
            acc[t] = __builtin_amdgcn_mfma_f32_16x16x32_bf16(                  \
                pf[0], VFC[t * 2 + 0], acc[t], 0, 0, 0);                       \
            acc[t] = __builtin_amdgcn_mfma_f32_16x16x32_bf16(                  \
                pf[1], VFC[t * 2 + 1], acc[t], 0, 0, 0);                       \
        }                                                                      \
        __builtin_amdgcn_s_setprio(0);                                         \
        if (!(LAST)) {                                                         \
            asm volatile("s_waitcnt vmcnt(8)" ::: "memory"); /* K-DMA only */  \
            __builtin_amdgcn_s_barrier();        /* V rides across */          \
            __builtin_amdgcn_sched_barrier(0);                                 \
        }                                                                      \
    }

    STAGE_K(0, kbase0);
    LOADV(vfA, kbase0);
    __syncthreads();                        // prologue: full drain, all ready

    for (int it = 0; it < 8; ++it) {
        TILE_BODY(2 * it,     0, vfA, vfB, false);
        if (it < 7) {
            TILE_BODY(2 * it + 1, 1, vfB, vfA, false);
        } else {
            TILE_BODY(2 * it + 1, 1, vfB, vfA, true);
        }
    }
#undef TILE_BODY
#undef STAGE_K
#undef LOADV

    // ---- partial stores (numerator un-normalized, denominator separate)
    float* nout = ksp ? part1 : num0;
    #pragma unroll
    for (int r = 0; r < 4; ++r) {
        int n = n0 + w * 16 + ((lane >> 4) << 2) + r;
        #pragma unroll
        for (int t = 0; t < 4; ++t)
            nout[((size_t)h * NTOK + n) * 64 + t * 16 + (lane & 15)] = acc[t][r];
    }
    if (lane < 16)
        lbuf[ksp * NQ + h * NTOK + n0 + w * 16 + lane] = lsum;
}

// ---------------------------------------------------------------------------
// out = (num0 + part1) / (l0 + l1), float4-vectorized.  393216 float4s.
// ---------------------------------------------------------------------------
__global__ __launch_bounds__(256) void combine_kernel(
    float* __restrict__ out, const float* __restrict__ part1,
    const float* __restrict__ lbuf)
{
    int gid = blockIdx.x * 256 + threadIdx.x;
    float4 a = ((const float4*)out)[gid];
    float4 b = ((const float4*)part1)[gid];
    int row = gid >> 4;
    float inv = 1.0f / (lbuf[row] + lbuf[NQ + row]);
    float4 o;
    o.x = (a.x + b.x) * inv; o.y = (a.y + b.y) * inv;
    o.z = (a.z + b.z) * inv; o.w = (a.w + b.w) * inv;
    ((float4*)out)[gid] = o;
}

// ---------------------------------------------------------------------------
extern "C" void kernel_launch(void* const* d_in, const int* in_sizes, int n_in,
                              void* d_out, int out_size, void* d_ws, size_t ws_size,
                              hipStream_t stream)
{
    const float* hs = (const float*)d_in[0];
    // d_in[1] = g, d_in[2] = attention_mask: feed only dead code -> unused.
    const float* Wq = (const float*)d_in[3];
    const float* bq = (const float*)d_in[4];
    const float* Wv = (const float*)d_in[5];
    const float* bv = (const float*)d_in[6];
    float* out = (float*)d_out;

    unsigned short* qbf   = (unsigned short*)d_ws;            // [2048*768] bf16
    unsigned short* vT    = qbf + (size_t)NTOK * HDIM;        // [768*2048] bf16
    float*          part1 = (float*)(vT + (size_t)HDIM * NTOK);   // [24576*64] f32
    float*          lbuf  = part1 + (size_t)NQ * 64;          // [2*24576] f32

    projnorm_kernel<<<dim3(12, 16, 2), 256, 0, stream>>>(
        hs, Wq, bq, Wv, bv, qbf, vT);
    attn_kernel<<<dim3(1536), 128, 0, stream>>>(qbf, vT, out, part1, lbuf);
    combine_kernel<<<dim3(1536), 256, 0, stream>>>(out, part1, lbuf);
}